// Round 3
// baseline (1577.684 us; speedup 1.0000x reference)
//
#include <hip/hip_runtime.h>
#include <hip/hip_bf16.h>
#include <stdint.h>

// Problem constants (LSTM_36825049596199)
#define B_    64
#define T_    512
#define EMB_  128
#define H_    128
#define G4    512            // 4*H
#define M_    (B_ * T_)      // 32768 rows for the input-projection GEMM

typedef __attribute__((ext_vector_type(8))) short  short8;   // 8 bf16 (4 VGPRs) MFMA frag
typedef __attribute__((ext_vector_type(4))) float  floatx4;  // MFMA acc frag
typedef __attribute__((ext_vector_type(2))) float  float2v;  // packed fp32 (v_pk_fma_f32)

#define GLDS(g, l) __builtin_amdgcn_global_load_lds( \
    (__attribute__((address_space(1))) void*)(g),    \
    (__attribute__((address_space(3))) void*)(l), 16, 0, 0)

__device__ __forceinline__ unsigned short f2bf_bits(float f) {
  __hip_bfloat16 h = __float2bfloat16(f);
  return *reinterpret_cast<unsigned short*>(&h);
}
__device__ __forceinline__ float bf_bits2f(unsigned short u) {
  unsigned int x = ((unsigned int)u) << 16;
  return __uint_as_float(x);
}
__device__ __forceinline__ float sigm(float x) {
  return __fdividef(1.0f, 1.0f + __expf(-x));
}
__device__ __forceinline__ float tanh_fast(float x) {
  // tanh(x) = 1 - 2/(e^{2x}+1); saturates correctly at +-inf
  return 1.0f - __fdividef(2.0f, __expf(2.0f * x) + 1.0f);
}

// LDS-only barrier: waits lgkmcnt(0) (LDS writes visible) then s_barrier,
// WITHOUT the vmcnt(0) drain __syncthreads() forces. In-flight global loads
// (xg prefetch) and stores (y) have no cross-thread consumers; the compiler
// still emits s_waitcnt vmcnt(N) before the prefetch result's USE, one full
// iteration later. This removes ~200-900 cyc of HBM/L2 latency from the
// per-step recurrence critical path.
__device__ __forceinline__ void barrier_lds_only() {
  __asm__ __volatile__("s_waitcnt lgkmcnt(0)\n\ts_barrier" ::: "memory");
}

// xg element type templated: float (precise) if workspace allows, bf16 otherwise.
__device__ __forceinline__ void  store_xg(float* p, float v)  { *p = v; }
__device__ __forceinline__ void  store_xg(unsigned short* p, float v) { *p = f2bf_bits(v); }
__device__ __forceinline__ float load_xg(const float* p)  { return *p; }
__device__ __forceinline__ float load_xg(const unsigned short* p) { return bf_bits2f(*p); }

// ---------------------------------------------------------------------------
// Embedding gather: x0[b,t,:] = bf16(emb[X[b,t],:]).  float4 in, ushort4 out.
__global__ void k_gather(const int* __restrict__ X, const float* __restrict__ emb,
                         unsigned short* __restrict__ x0) {
  int i = blockIdx.x * 256 + threadIdx.x;       // over M_*32 float4 groups
  int row = i >> 5, c4 = i & 31;
  float4 v = ((const float4*)emb)[(size_t)X[row] * 32 + c4];
  ushort4 o;
  o.x = f2bf_bits(v.x); o.y = f2bf_bits(v.y); o.z = f2bf_bits(v.z); o.w = f2bf_bits(v.w);
  ((ushort4*)x0)[i] = o;
}

// Per-layer weight prep: w_ih -> bf16, bias_sum = b_ih + b_hh.
__global__ void k_prep(const float* __restrict__ w, const float* __restrict__ bi,
                       const float* __restrict__ bh, unsigned short* __restrict__ wb,
                       float* __restrict__ bias, int nw) {
  int i = blockIdx.x * blockDim.x + threadIdx.x;
  int stride = gridDim.x * blockDim.x;
  for (int k = i; k < nw; k += stride) wb[k] = f2bf_bits(w[k]);
  for (int k = i; k < 2 * G4; k += stride) bias[k] = bi[k] + bh[k];
}

// ---------------------------------------------------------------------------
// Input-projection GEMM (NT): xg[dir][m][n] = sum_k A[m][k]*W[dir][n][k] + bias[dir][n]
// 128x128 tile, BK=32, 256 threads. global_load_lds width-16 staging; k-chunk
// XOR swizzle so ds_read_b128 frag reads are 2-way (free).
template <typename XG_T>
__global__ __launch_bounds__(256, 2) void k_gemm(
    const unsigned short* __restrict__ A,   // [M_, K] bf16 row-major
    const unsigned short* __restrict__ W,   // [2][G4][K] bf16 row-major
    const float* __restrict__ bias,         // [2][G4]
    XG_T* __restrict__ xg,                  // [2][M_][G4]
    int K) {
  __shared__ unsigned short sA[128 * 32];
  __shared__ unsigned short sB[128 * 32];
  const int tid  = threadIdx.x;
  const int lane = tid & 63;
  const int wave = tid >> 6;
  const int mt = blockIdx.x, nt = blockIdx.y, dir = blockIdx.z;
  const size_t Arow0 = (size_t)mt * 128;
  const int    Ncol0 = nt * 128;
  const unsigned short* Wd = W + (size_t)dir * G4 * K;

  const int srow = tid >> 2;                           // LDS row (issue 0), +64 for issue 1
  const int qlog = (tid & 3) ^ ((tid >> 4) & 3);       // swizzled logical k-chunk to fetch
  auto ldsA0 = (__attribute__((address_space(3))) void*)(sA + wave * 512);
  auto ldsA1 = (__attribute__((address_space(3))) void*)(sA + 2048 + wave * 512);
  auto ldsB0 = (__attribute__((address_space(3))) void*)(sB + wave * 512);
  auto ldsB1 = (__attribute__((address_space(3))) void*)(sB + 2048 + wave * 512);

  floatx4 acc[4][4];
#pragma unroll
  for (int i = 0; i < 4; ++i)
#pragma unroll
    for (int j = 0; j < 4; ++j) acc[i][j] = (floatx4)0.0f;

  const int wrow = (wave >> 1) * 64, wcol = (wave & 1) * 64;
  const int frow = lane & 15;
  const int fq   = lane >> 4;

  for (int kt = 0; kt < K; kt += 32) {
    const unsigned short* gA0 = A  + (Arow0 + srow) * (size_t)K + kt + qlog * 8;
    const unsigned short* gB0 = Wd + (size_t)(Ncol0 + srow) * K + kt + qlog * 8;
    GLDS(gA0, ldsA0);
    GLDS(gA0 + (size_t)64 * K, ldsA1);
    GLDS(gB0, ldsB0);
    GLDS(gB0 + (size_t)64 * K, ldsB1);
    __syncthreads();   // staged data must be visible: full drain required here

    short8 af[4], bf[4];
#pragma unroll
    for (int i = 0; i < 4; ++i) {
      int r  = wrow + 16 * i + frow;
      int rn = wcol + 16 * i + frow;
      af[i] = *(const short8*)(sA + r  * 32 + ((fq ^ ((r  >> 2) & 3)) * 8));
      bf[i] = *(const short8*)(sB + rn * 32 + ((fq ^ ((rn >> 2) & 3)) * 8));
    }
#pragma unroll
    for (int i = 0; i < 4; ++i)
#pragma unroll
      for (int j = 0; j < 4; ++j)
        acc[i][j] = __builtin_amdgcn_mfma_f32_16x16x32_bf16(af[i], bf[j], acc[i][j], 0, 0, 0);
    __syncthreads();
  }

  // Epilogue: C/D layout col=lane&15, row=(lane>>4)*4+reg  [m89-verified]
  const int r0 = (lane >> 4) * 4;
  const int cc = lane & 15;
  XG_T* xgd = xg + (size_t)dir * M_ * G4;
#pragma unroll
  for (int j = 0; j < 4; ++j) {
    int gcol = Ncol0 + wcol + 16 * j + cc;
    float bs = bias[dir * G4 + gcol];
#pragma unroll
    for (int i = 0; i < 4; ++i) {
      size_t rowb = Arow0 + wrow + 16 * i + r0;
#pragma unroll
      for (int r = 0; r < 4; ++r)
        store_xg(&xgd[(rowb + r) * G4 + gcol], acc[i][j][r] + bs);
    }
  }
}

// ---------------------------------------------------------------------------
// Recurrent scan, one block per (dir,b). 512 threads = 8 waves; wave w owns
// units u in [16w,16w+16). Lane = (p=lane>>4, ul=lane&15); thread holds
// W_hh[g*128+u][p*32 .. p*32+32) for g=0..3 -> 128 fp32 VGPRs as float2
// (v_pk_fma_f32). Per step (single LDS-only barrier, ping-pong h in LDS):
//   8x ds_read_b128 of h slice (16-lane broadcast, 4 unique addrs, skewed)
//   64 pk_fma -> 4 gate partials; +xg (1 dword/lane, gate p) pre-reduction
//   2x shfl_xor(16,32) in-wave reduce -> full pre-acts replicated over p
//   nonlinearities replicated over p-lanes; c replicated in regs
//   p==0 lanes write h ping-pong + y store (never drained in-loop)
template <typename XG_T>
__global__ __launch_bounds__(512, 2) void k_scan(
    const float* __restrict__ Whh,   // [2][G4][H_]
    const float* __restrict__ hx0,   // [2][B_][H_] (layer base)
    const float* __restrict__ cx0,
    const XG_T* __restrict__ xg,     // [2][M_][G4]
    unsigned short* __restrict__ y)  // [B_][T_][2*H_] bf16
{
  const int b   = blockIdx.x & 63;
  const int dir = blockIdx.x >> 6;
  const int tid = threadIdx.x;
  const int lane = tid & 63;
  const int wave = tid >> 6;
  const int p  = lane >> 4;
  const int ul = lane & 15;
  const int u  = wave * 16 + ul;

  // skewed h: element u stored at u + (u>>5)*8 -> the 4 p-slice float4 reads
  // hit disjoint bank groups. 160 floats per ping-pong buffer.
  __shared__ __align__(16) float h_lds[2][160];

  // weights: w2[g][q] covers k = p*32 + 2q, 2q+1
  float2v w2[4][16];
#pragma unroll
  for (int g = 0; g < 4; ++g) {
    const float* wr = Whh + ((size_t)dir * G4 + g * H_ + u) * H_ + p * 32;
#pragma unroll
    for (int q = 0; q < 8; ++q) {
      float4 v = *(const float4*)(wr + q * 4);
      w2[g][2 * q]     = float2v{v.x, v.y};
      w2[g][2 * q + 1] = float2v{v.z, v.w};
    }
  }

  float c = cx0[(size_t)dir * B_ * H_ + b * H_ + u];   // replicated over p
  if (p == 0) {
    float h0 = hx0[(size_t)dir * B_ * H_ + b * H_ + u];
    h_lds[0][u + (u >> 5) * 8] = h0;
  }
  __syncthreads();   // once, before the loop: full drain is fine here

  const XG_T* xgb = xg + ((size_t)dir * M_ + (size_t)b * T_) * G4;

  // prefetched xg for current step: gate p, unit u (1 dword/lane)
  float xv = load_xg(xgb + (size_t)(dir ? (T_ - 1) : 0) * G4 + p * H_ + u);

  for (int t = 0; t < T_; ++t) {
    // prefetch next step's xg (distance 1: ~600+ cyc to cover HBM/L3 latency;
    // its waitcnt lands before next iteration's use, NOT at the barrier)
    float xn = 0.0f;
    if (t + 1 < T_) {
      int ttn = dir ? (T_ - 2 - t) : (t + 1);
      xn = load_xg(xgb + (size_t)ttn * G4 + p * H_ + u);
    }

    // FMA phase: h slice [p*32, p*32+32) from skewed LDS (base p*40 dwords)
    const float4* h4 = (const float4*)(h_lds[t & 1] + p * 40);
    float2v s0 = {0, 0}, s1 = {0, 0}, s2 = {0, 0}, s3 = {0, 0};
#pragma unroll
    for (int q = 0; q < 8; ++q) {
      float4 hv = h4[q];
      float2v ha = {hv.x, hv.y}, hb = {hv.z, hv.w};
      s0 = __builtin_elementwise_fma(w2[0][2 * q], ha, s0);
      s1 = __builtin_elementwise_fma(w2[1][2 * q], ha, s1);
      s2 = __builtin_elementwise_fma(w2[2][2 * q], ha, s2);
      s3 = __builtin_elementwise_fma(w2[3][2 * q], ha, s3);
      s0 = __builtin_elementwise_fma(w2[0][2 * q + 1], hb, s0);
      s1 = __builtin_elementwise_fma(w2[1][2 * q + 1], hb, s1);
      s2 = __builtin_elementwise_fma(w2[2][2 * q + 1], hb, s2);
      s3 = __builtin_elementwise_fma(w2[3][2 * q + 1], hb, s3);
    }
    float g0 = s0.x + s0.y, g1 = s1.x + s1.y, g2 = s2.x + s2.y, g3 = s3.x + s3.y;
    // fold xg for gate p (added exactly once across the p-reduction)
    if (p == 0) g0 += xv; else if (p == 1) g1 += xv;
    else if (p == 2) g2 += xv; else g3 += xv;

    // in-wave reduction over p (lanes xor 16, 32) -> full sums replicated
    g0 += __shfl_xor(g0, 16); g0 += __shfl_xor(g0, 32);
    g1 += __shfl_xor(g1, 16); g1 += __shfl_xor(g1, 32);
    g2 += __shfl_xor(g2, 16); g2 += __shfl_xor(g2, 32);
    g3 += __shfl_xor(g3, 16); g3 += __shfl_xor(g3, 32);

    // nonlinearities (replicated over p-lanes; torch gate order i,f,g,o)
    float iv = sigm(g0), fv = sigm(g1), gv = tanh_fast(g2), ov = sigm(g3);
    c = fmaf(fv, c, iv * gv);
    float h = ov * tanh_fast(c);

    if (p == 0) {
      h_lds[(t + 1) & 1][u + (u >> 5) * 8] = h;
      int tt = dir ? (T_ - 1 - t) : t;
      y[((size_t)b * T_ + tt) * (2 * H_) + dir * H_ + u] = f2bf_bits(h);
    }
    barrier_lds_only();   // h ping-pong visible; NO vmcnt drain
    xv = xn;
  }
}

// ---------------------------------------------------------------------------
// Head: out[b] = y2[b, T-1, :] . lin_w + lin_b   (64 outputs)
__global__ void k_head(const unsigned short* __restrict__ y2, const float* __restrict__ lw,
                       const float* __restrict__ lb, float* __restrict__ out) {
  int b = blockIdx.x, l = threadIdx.x;   // 64 threads = 1 wave
  const unsigned short* row = y2 + ((size_t)b * T_ + (T_ - 1)) * (2 * H_);
  float s = 0;
#pragma unroll
  for (int k = 0; k < 4; ++k) s += bf_bits2f(row[l + 64 * k]) * lw[l + 64 * k];
#pragma unroll
  for (int off = 32; off > 0; off >>= 1) s += __shfl_down(s, off);
  if (l == 0) out[b] = s + lb[0];
}

// ---------------------------------------------------------------------------
template <typename XG_T>
static inline void run_layers(const float* const* w_hh,
                              const unsigned short* x0,
                              unsigned short* y0, unsigned short* y1, unsigned short* y2,
                              const unsigned short* wb0, const unsigned short* wb1,
                              const unsigned short* wb2,
                              const float* bias0, const float* bias1, const float* bias2,
                              const float* hx, const float* cx,
                              XG_T* xg, hipStream_t stream) {
  dim3 gg(M_ / 128, G4 / 128, 2);
  k_gemm<XG_T><<<gg, 256, 0, stream>>>(x0, wb0, bias0, xg, EMB_);
  k_scan<XG_T><<<128, 512, 0, stream>>>(w_hh[0], hx, cx, xg, y0);
  k_gemm<XG_T><<<gg, 256, 0, stream>>>(y0, wb1, bias1, xg, 2 * H_);
  k_scan<XG_T><<<128, 512, 0, stream>>>(w_hh[1], hx + 2 * B_ * H_, cx + 2 * B_ * H_, xg, y1);
  k_gemm<XG_T><<<gg, 256, 0, stream>>>(y1, wb2, bias2, xg, 2 * H_);
  k_scan<XG_T><<<128, 512, 0, stream>>>(w_hh[2], hx + 4 * B_ * H_, cx + 4 * B_ * H_, xg, y2);
}

extern "C" void kernel_launch(void* const* d_in, const int* in_sizes, int n_in,
                              void* d_out, int out_size, void* d_ws, size_t ws_size,
                              hipStream_t stream) {
  const int*   X   = (const int*)d_in[0];
  const float* emb = (const float*)d_in[1];
  const float* hx  = (const float*)d_in[2];
  const float* cx  = (const float*)d_in[3];
  const float* lw  = (const float*)d_in[4];
  const float* lb  = (const float*)d_in[5];
  const float* w_ih[3] = {(const float*)d_in[6],  (const float*)d_in[10], (const float*)d_in[14]};
  const float* w_hh[3] = {(const float*)d_in[7],  (const float*)d_in[11], (const float*)d_in[15]};
  const float* b_ih[3] = {(const float*)d_in[8],  (const float*)d_in[12], (const float*)d_in[16]};
  const float* b_hh[3] = {(const float*)d_in[9],  (const float*)d_in[13], (const float*)d_in[17]};
  float* out = (float*)d_out;

  char* ws = (char*)d_ws;
  size_t off = 0;
  auto carve = [&](size_t bytes) {
    char* p = ws + off;
    off = (off + bytes + 255) & ~(size_t)255;
    return p;
  };
  unsigned short* x0  = (unsigned short*)carve((size_t)M_ * EMB_ * 2);
  unsigned short* y0  = (unsigned short*)carve((size_t)M_ * 2 * H_ * 2);
  unsigned short* y1  = (unsigned short*)carve((size_t)M_ * 2 * H_ * 2);
  unsigned short* y2  = (unsigned short*)carve((size_t)M_ * 2 * H_ * 2);
  unsigned short* wb0 = (unsigned short*)carve((size_t)2 * G4 * EMB_ * 2);
  unsigned short* wb1 = (unsigned short*)carve((size_t)2 * G4 * 2 * H_ * 2);
  unsigned short* wb2 = (unsigned short*)carve((size_t)2 * G4 * 2 * H_ * 2);
  float* bias0 = (float*)carve(2 * G4 * 4);
  float* bias1 = (float*)carve(2 * G4 * 4);
  float* bias2 = (float*)carve(2 * G4 * 4);
  const size_t xg_f32_bytes = (size_t)2 * M_ * G4 * 4;
  const bool use_f32 = (off + xg_f32_bytes) <= ws_size;   // prefer fp32 xg when it fits
  void* xg = carve(use_f32 ? xg_f32_bytes : xg_f32_bytes / 2);

  k_prep<<<256, 256, 0, stream>>>(w_ih[0], b_ih[0], b_hh[0], wb0, bias0, 2 * G4 * EMB_);
  k_prep<<<256, 256, 0, stream>>>(w_ih[1], b_ih[1], b_hh[1], wb1, bias1, 2 * G4 * 2 * H_);
  k_prep<<<256, 256, 0, stream>>>(w_ih[2], b_ih[2], b_hh[2], wb2, bias2, 2 * G4 * 2 * H_);
  k_gather<<<(M_ * 32) / 256, 256, 0, stream>>>(X, emb, x0);

  if (use_f32)
    run_layers<float>(w_hh, x0, y0, y1, y2, wb0, wb1, wb2, bias0, bias1, bias2,
                      hx, cx, (float*)xg, stream);
  else
    run_layers<unsigned short>(w_hh, x0, y0, y1, y2, wb0, wb1, wb2, bias0, bias1, bias2,
                               hx, cx, (unsigned short*)xg, stream);

  k_head<<<64, 64, 0, stream>>>(y2, lw, lb, out);
}

// Round 4
// 1482.677 us; speedup vs baseline: 1.0641x; 1.0641x over previous
//
#include <hip/hip_runtime.h>
#include <hip/hip_bf16.h>
#include <stdint.h>

// Problem constants (LSTM_36825049596199)
#define B_    64
#define T_    512
#define EMB_  128
#define H_    128
#define G4    512            // 4*H
#define M_    (B_ * T_)      // 32768 rows for the input-projection GEMM

typedef __attribute__((ext_vector_type(8))) short  short8;   // 8 bf16 (4 VGPRs) MFMA frag
typedef __attribute__((ext_vector_type(4))) float  floatx4;  // MFMA acc frag
typedef __attribute__((ext_vector_type(2))) float  float2v;  // packed fp32 (v_pk_fma_f32)

#define GLDS(g, l) __builtin_amdgcn_global_load_lds( \
    (__attribute__((address_space(1))) void*)(g),    \
    (__attribute__((address_space(3))) void*)(l), 16, 0, 0)

__device__ __forceinline__ unsigned short f2bf_bits(float f) {
  __hip_bfloat16 h = __float2bfloat16(f);
  return *reinterpret_cast<unsigned short*>(&h);
}
__device__ __forceinline__ float bf_bits2f(unsigned short u) {
  unsigned int x = ((unsigned int)u) << 16;
  return __uint_as_float(x);
}
__device__ __forceinline__ float sigm(float x) {
  return __fdividef(1.0f, 1.0f + __expf(-x));
}
__device__ __forceinline__ float tanh_fast(float x) {
  // tanh(x) = 1 - 2/(e^{2x}+1); saturates correctly at +-inf
  return 1.0f - __fdividef(2.0f, __expf(2.0f * x) + 1.0f);
}

// Butterfly sum across a quad (lanes 4i..4i+3) using DPP quad_perm — pure
// VALU, no DS-pipe traffic (unlike __shfl_xor -> ds_bpermute). All 4 lanes
// end with the quad total. ctrl 0xB1 = perm[1,0,3,2] (xor1), 0x4E =
// perm[2,3,0,1] (xor2).
__device__ __forceinline__ float quad_bfly_add(float x) {
  float y = x + __int_as_float(
      __builtin_amdgcn_mov_dpp(__float_as_int(x), 0xB1, 0xF, 0xF, true));
  return y + __int_as_float(
      __builtin_amdgcn_mov_dpp(__float_as_int(y), 0x4E, 0xF, 0xF, true));
}

// xg element type templated: float (precise) if workspace allows, bf16 otherwise.
__device__ __forceinline__ void  store_xg(float* p, float v)  { *p = v; }
__device__ __forceinline__ void  store_xg(unsigned short* p, float v) { *p = f2bf_bits(v); }
__device__ __forceinline__ float load_xg(const float* p)  { return *p; }
__device__ __forceinline__ float load_xg(const unsigned short* p) { return bf_bits2f(*p); }

// ---------------------------------------------------------------------------
// Embedding gather: x0[b,t,:] = bf16(emb[X[b,t],:]).  float4 in, ushort4 out.
__global__ void k_gather(const int* __restrict__ X, const float* __restrict__ emb,
                         unsigned short* __restrict__ x0) {
  int i = blockIdx.x * 256 + threadIdx.x;       // over M_*32 float4 groups
  int row = i >> 5, c4 = i & 31;
  float4 v = ((const float4*)emb)[(size_t)X[row] * 32 + c4];
  ushort4 o;
  o.x = f2bf_bits(v.x); o.y = f2bf_bits(v.y); o.z = f2bf_bits(v.z); o.w = f2bf_bits(v.w);
  ((ushort4*)x0)[i] = o;
}

// Per-layer weight prep: w_ih -> bf16, bias_sum = b_ih + b_hh.
__global__ void k_prep(const float* __restrict__ w, const float* __restrict__ bi,
                       const float* __restrict__ bh, unsigned short* __restrict__ wb,
                       float* __restrict__ bias, int nw) {
  int i = blockIdx.x * blockDim.x + threadIdx.x;
  int stride = gridDim.x * blockDim.x;
  for (int k = i; k < nw; k += stride) wb[k] = f2bf_bits(w[k]);
  for (int k = i; k < 2 * G4; k += stride) bias[k] = bi[k] + bh[k];
}

// ---------------------------------------------------------------------------
// Input-projection GEMM (NT): xg[dir][m][n] = sum_k A[m][k]*W[dir][n][k] + bias[dir][n]
// 128x128 tile, BK=32, 256 threads. global_load_lds width-16 staging; k-chunk
// XOR swizzle so ds_read_b128 frag reads are 2-way (free).
template <typename XG_T>
__global__ __launch_bounds__(256, 2) void k_gemm(
    const unsigned short* __restrict__ A,   // [M_, K] bf16 row-major
    const unsigned short* __restrict__ W,   // [2][G4][K] bf16 row-major
    const float* __restrict__ bias,         // [2][G4]
    XG_T* __restrict__ xg,                  // [2][M_][G4]
    int K) {
  __shared__ unsigned short sA[128 * 32];
  __shared__ unsigned short sB[128 * 32];
  const int tid  = threadIdx.x;
  const int lane = tid & 63;
  const int wave = tid >> 6;
  const int mt = blockIdx.x, nt = blockIdx.y, dir = blockIdx.z;
  const size_t Arow0 = (size_t)mt * 128;
  const int    Ncol0 = nt * 128;
  const unsigned short* Wd = W + (size_t)dir * G4 * K;

  const int srow = tid >> 2;                           // LDS row (issue 0), +64 for issue 1
  const int qlog = (tid & 3) ^ ((tid >> 4) & 3);       // swizzled logical k-chunk to fetch
  auto ldsA0 = (__attribute__((address_space(3))) void*)(sA + wave * 512);
  auto ldsA1 = (__attribute__((address_space(3))) void*)(sA + 2048 + wave * 512);
  auto ldsB0 = (__attribute__((address_space(3))) void*)(sB + wave * 512);
  auto ldsB1 = (__attribute__((address_space(3))) void*)(sB + 2048 + wave * 512);

  floatx4 acc[4][4];
#pragma unroll
  for (int i = 0; i < 4; ++i)
#pragma unroll
    for (int j = 0; j < 4; ++j) acc[i][j] = (floatx4)0.0f;

  const int wrow = (wave >> 1) * 64, wcol = (wave & 1) * 64;
  const int frow = lane & 15;
  const int fq   = lane >> 4;

  for (int kt = 0; kt < K; kt += 32) {
    const unsigned short* gA0 = A  + (Arow0 + srow) * (size_t)K + kt + qlog * 8;
    const unsigned short* gB0 = Wd + (size_t)(Ncol0 + srow) * K + kt + qlog * 8;
    GLDS(gA0, ldsA0);
    GLDS(gA0 + (size_t)64 * K, ldsA1);
    GLDS(gB0, ldsB0);
    GLDS(gB0 + (size_t)64 * K, ldsB1);
    __syncthreads();   // staged data must be visible: full drain required here

    short8 af[4], bf[4];
#pragma unroll
    for (int i = 0; i < 4; ++i) {
      int r  = wrow + 16 * i + frow;
      int rn = wcol + 16 * i + frow;
      af[i] = *(const short8*)(sA + r  * 32 + ((fq ^ ((r  >> 2) & 3)) * 8));
      bf[i] = *(const short8*)(sB + rn * 32 + ((fq ^ ((rn >> 2) & 3)) * 8));
    }
#pragma unroll
    for (int i = 0; i < 4; ++i)
#pragma unroll
      for (int j = 0; j < 4; ++j)
        acc[i][j] = __builtin_amdgcn_mfma_f32_16x16x32_bf16(af[i], bf[j], acc[i][j], 0, 0, 0);
    __syncthreads();
  }

  // Epilogue: C/D layout col=lane&15, row=(lane>>4)*4+reg  [m89-verified]
  const int r0 = (lane >> 4) * 4;
  const int cc = lane & 15;
  XG_T* xgd = xg + (size_t)dir * M_ * G4;
#pragma unroll
  for (int j = 0; j < 4; ++j) {
    int gcol = Ncol0 + wcol + 16 * j + cc;
    float bs = bias[dir * G4 + gcol];
#pragma unroll
    for (int i = 0; i < 4; ++i) {
      size_t rowb = Arow0 + wrow + 16 * i + r0;
#pragma unroll
      for (int r = 0; r < 4; ++r)
        store_xg(&xgd[(rowb + r) * G4 + gcol], acc[i][j][r] + bs);
    }
  }
}

// ---------------------------------------------------------------------------
// Recurrent scan, one block per (dir,b). 512 threads = 8 waves; wave w owns
// units u in [16w,16w+16). Lane = (ul=lane>>2, p=lane&3); thread holds
// W_hh[g*128+u][p*32 .. p*32+32) for g=0..3 -> 128 fp32 VGPRs as float2
// (v_pk_fma_f32). Per step (single __syncthreads, ping-pong h in LDS):
//   8x ds_read_b128 of h slice (4 unique addrs/instr, bank-disjoint, 16-lane
//     broadcast) -- the ONLY DS-pipe reads per step
//   64 pk_fma -> 4 gate partials; +xg (1 dword/lane, gate p) pre-reduction
//   8x DPP quad-butterfly adds (VALU pipe, replaces ds_bpermute shuffles)
//   nonlinearities replicated over quad lanes; c replicated in regs
//   p==0 lanes write h ping-pong (1 ds_write) + y store
// DS instrs/CU/step: 8 waves*(8 reads + 1 write) = 72 (was 136 w/ shuffles).
template <typename XG_T>
__global__ __launch_bounds__(512, 2) void k_scan(
    const float* __restrict__ Whh,   // [2][G4][H_]
    const float* __restrict__ hx0,   // [2][B_][H_] (layer base)
    const float* __restrict__ cx0,
    const XG_T* __restrict__ xg,     // [2][M_][G4]
    unsigned short* __restrict__ y)  // [B_][T_][2*H_] bf16
{
  const int b   = blockIdx.x & 63;
  const int dir = blockIdx.x >> 6;
  const int tid = threadIdx.x;
  const int lane = tid & 63;
  const int wave = tid >> 6;
  const int p  = lane & 3;        // k-slice index (quad position)
  const int ul = lane >> 2;       // unit within wave (0..15)
  const int u  = wave * 16 + ul;

  // skewed h: element u stored at u + (u>>5)*8 -> the 4 p-slice float4 reads
  // hit disjoint bank groups (bases p*40 dwords). 160 floats per buffer.
  __shared__ __align__(16) float h_lds[2][160];

  // weights: w2[g][q] covers k = p*32 + 2q, 2q+1
  float2v w2[4][16];
#pragma unroll
  for (int g = 0; g < 4; ++g) {
    const float* wr = Whh + ((size_t)dir * G4 + g * H_ + u) * H_ + p * 32;
#pragma unroll
    for (int q = 0; q < 8; ++q) {
      float4 v = *(const float4*)(wr + q * 4);
      w2[g][2 * q]     = float2v{v.x, v.y};
      w2[g][2 * q + 1] = float2v{v.z, v.w};
    }
  }

  float c = cx0[(size_t)dir * B_ * H_ + b * H_ + u];   // replicated over quad
  if (p == 0) {
    float h0 = hx0[(size_t)dir * B_ * H_ + b * H_ + u];
    h_lds[0][u + (u >> 5) * 8] = h0;
  }
  __syncthreads();

  const XG_T* xgb = xg + ((size_t)dir * M_ + (size_t)b * T_) * G4;

  // prefetched xg for current step: gate p, unit u (1 dword/lane)
  float xv = load_xg(xgb + (size_t)(dir ? (T_ - 1) : 0) * G4 + p * H_ + u);

  for (int t = 0; t < T_; ++t) {
    // prefetch next step's xg (distance 1: full step ~1000+ cyc covers latency)
    float xn = 0.0f;
    if (t + 1 < T_) {
      int ttn = dir ? (T_ - 2 - t) : (t + 1);
      xn = load_xg(xgb + (size_t)ttn * G4 + p * H_ + u);
    }

    // FMA phase: h slice [p*32, p*32+32) from skewed LDS (base p*40 dwords)
    const float4* h4 = (const float4*)(h_lds[t & 1] + p * 40);
    float2v s0 = {0, 0}, s1 = {0, 0}, s2 = {0, 0}, s3 = {0, 0};
#pragma unroll
    for (int q = 0; q < 8; ++q) {
      float4 hv = h4[q];
      float2v ha = {hv.x, hv.y}, hb = {hv.z, hv.w};
      s0 = __builtin_elementwise_fma(w2[0][2 * q], ha, s0);
      s1 = __builtin_elementwise_fma(w2[1][2 * q], ha, s1);
      s2 = __builtin_elementwise_fma(w2[2][2 * q], ha, s2);
      s3 = __builtin_elementwise_fma(w2[3][2 * q], ha, s3);
      s0 = __builtin_elementwise_fma(w2[0][2 * q + 1], hb, s0);
      s1 = __builtin_elementwise_fma(w2[1][2 * q + 1], hb, s1);
      s2 = __builtin_elementwise_fma(w2[2][2 * q + 1], hb, s2);
      s3 = __builtin_elementwise_fma(w2[3][2 * q + 1], hb, s3);
    }
    float g0 = s0.x + s0.y, g1 = s1.x + s1.y, g2 = s2.x + s2.y, g3 = s3.x + s3.y;
    // fold xg for gate p (added exactly once across the quad reduction)
    g0 += (p == 0) ? xv : 0.0f;
    g1 += (p == 1) ? xv : 0.0f;
    g2 += (p == 2) ? xv : 0.0f;
    g3 += (p == 3) ? xv : 0.0f;

    // quad butterfly reduction over p — DPP (VALU), no DS traffic
    g0 = quad_bfly_add(g0);
    g1 = quad_bfly_add(g1);
    g2 = quad_bfly_add(g2);
    g3 = quad_bfly_add(g3);

    // nonlinearities (replicated over quad lanes; torch gate order i,f,g,o)
    float iv = sigm(g0), fv = sigm(g1), gv = tanh_fast(g2), ov = sigm(g3);
    c = fmaf(fv, c, iv * gv);
    float h = ov * tanh_fast(c);

    if (p == 0) {
      h_lds[(t + 1) & 1][u + (u >> 5) * 8] = h;
      int tt = dir ? (T_ - 1 - t) : t;
      y[((size_t)b * T_ + tt) * (2 * H_) + dir * H_ + u] = f2bf_bits(h);
    }
    __syncthreads();   // h ping-pong visible (WAR-safe: write buf != read buf)
    xv = xn;
  }
}

// ---------------------------------------------------------------------------
// Head: out[b] = y2[b, T-1, :] . lin_w + lin_b   (64 outputs)
__global__ void k_head(const unsigned short* __restrict__ y2, const float* __restrict__ lw,
                       const float* __restrict__ lb, float* __restrict__ out) {
  int b = blockIdx.x, l = threadIdx.x;   // 64 threads = 1 wave
  const unsigned short* row = y2 + ((size_t)b * T_ + (T_ - 1)) * (2 * H_);
  float s = 0;
#pragma unroll
  for (int k = 0; k < 4; ++k) s += bf_bits2f(row[l + 64 * k]) * lw[l + 64 * k];
#pragma unroll
  for (int off = 32; off > 0; off >>= 1) s += __shfl_down(s, off);
  if (l == 0) out[b] = s + lb[0];
}

// ---------------------------------------------------------------------------
template <typename XG_T>
static inline void run_layers(const float* const* w_hh,
                              const unsigned short* x0,
                              unsigned short* y0, unsigned short* y1, unsigned short* y2,
                              const unsigned short* wb0, const unsigned short* wb1,
                              const unsigned short* wb2,
                              const float* bias0, const float* bias1, const float* bias2,
                              const float* hx, const float* cx,
                              XG_T* xg, hipStream_t stream) {
  dim3 gg(M_ / 128, G4 / 128, 2);
  k_gemm<XG_T><<<gg, 256, 0, stream>>>(x0, wb0, bias0, xg, EMB_);
  k_scan<XG_T><<<128, 512, 0, stream>>>(w_hh[0], hx, cx, xg, y0);
  k_gemm<XG_T><<<gg, 256, 0, stream>>>(y0, wb1, bias1, xg, 2 * H_);
  k_scan<XG_T><<<128, 512, 0, stream>>>(w_hh[1], hx + 2 * B_ * H_, cx + 2 * B_ * H_, xg, y1);
  k_gemm<XG_T><<<gg, 256, 0, stream>>>(y1, wb2, bias2, xg, 2 * H_);
  k_scan<XG_T><<<128, 512, 0, stream>>>(w_hh[2], hx + 4 * B_ * H_, cx + 4 * B_ * H_, xg, y2);
}

extern "C" void kernel_launch(void* const* d_in, const int* in_sizes, int n_in,
                              void* d_out, int out_size, void* d_ws, size_t ws_size,
                              hipStream_t stream) {
  const int*   X   = (const int*)d_in[0];
  const float* emb = (const float*)d_in[1];
  const float* hx  = (const float*)d_in[2];
  const float* cx  = (const float*)d_in[3];
  const float* lw  = (const float*)d_in[4];
  const float* lb  = (const float*)d_in[5];
  const float* w_ih[3] = {(const float*)d_in[6],  (const float*)d_in[10], (const float*)d_in[14]};
  const float* w_hh[3] = {(const float*)d_in[7],  (const float*)d_in[11], (const float*)d_in[15]};
  const float* b_ih[3] = {(const float*)d_in[8],  (const float*)d_in[12], (const float*)d_in[16]};
  const float* b_hh[3] = {(const float*)d_in[9],  (const float*)d_in[13], (const float*)d_in[17]};
  float* out = (float*)d_out;

  char* ws = (char*)d_ws;
  size_t off = 0;
  auto carve = [&](size_t bytes) {
    char* p = ws + off;
    off = (off + bytes + 255) & ~(size_t)255;
    return p;
  };
  unsigned short* x0  = (unsigned short*)carve((size_t)M_ * EMB_ * 2);
  unsigned short* y0  = (unsigned short*)carve((size_t)M_ * 2 * H_ * 2);
  unsigned short* y1  = (unsigned short*)carve((size_t)M_ * 2 * H_ * 2);
  unsigned short* y2  = (unsigned short*)carve((size_t)M_ * 2 * H_ * 2);
  unsigned short* wb0 = (unsigned short*)carve((size_t)2 * G4 * EMB_ * 2);
  unsigned short* wb1 = (unsigned short*)carve((size_t)2 * G4 * 2 * H_ * 2);
  unsigned short* wb2 = (unsigned short*)carve((size_t)2 * G4 * 2 * H_ * 2);
  float* bias0 = (float*)carve(2 * G4 * 4);
  float* bias1 = (float*)carve(2 * G4 * 4);
  float* bias2 = (float*)carve(2 * G4 * 4);
  const size_t xg_f32_bytes = (size_t)2 * M_ * G4 * 4;
  const bool use_f32 = (off + xg_f32_bytes) <= ws_size;   // prefer fp32 xg when it fits
  void* xg = carve(use_f32 ? xg_f32_bytes : xg_f32_bytes / 2);

  k_prep<<<256, 256, 0, stream>>>(w_ih[0], b_ih[0], b_hh[0], wb0, bias0, 2 * G4 * EMB_);
  k_prep<<<256, 256, 0, stream>>>(w_ih[1], b_ih[1], b_hh[1], wb1, bias1, 2 * G4 * 2 * H_);
  k_prep<<<256, 256, 0, stream>>>(w_ih[2], b_ih[2], b_hh[2], wb2, bias2, 2 * G4 * 2 * H_);
  k_gather<<<(M_ * 32) / 256, 256, 0, stream>>>(X, emb, x0);

  if (use_f32)
    run_layers<float>(w_hh, x0, y0, y1, y2, wb0, wb1, wb2, bias0, bias1, bias2,
                      hx, cx, (float*)xg, stream);
  else
    run_layers<unsigned short>(w_hh, x0, y0, y1, y2, wb0, wb1, wb2, bias0, bias1, bias2,
                               hx, cx, (unsigned short*)xg, stream);

  k_head<<<64, 64, 0, stream>>>(y2, lw, lb, out);
}